// Round 1
// baseline (243.996 us; speedup 1.0000x reference)
//
#include <hip/hip_runtime.h>

// ---------------------------------------------------------------------------
// AgglutinativeAttention: hs->QKV proj -> morpho-biased softmax attn -> out proj
// B=4 S=1024 H=1024 NH=16 HD=64.  All GEMM-shaped compute in bf16 MFMA 16x16x32.
// ---------------------------------------------------------------------------

#define Bc 4
#define Sc 1024
#define Hc 1024
#define NHc 16
#define HDc 64
#define Mc 4096
#define SCALEc 0.125f

typedef float  f32x4  __attribute__((ext_vector_type(4)));
typedef short  s16x8  __attribute__((ext_vector_type(8)));
typedef unsigned short u16x4 __attribute__((ext_vector_type(4)));
typedef unsigned short u16x8 __attribute__((ext_vector_type(8)));

__device__ __forceinline__ unsigned short f2bf(float f) {
  union { float f; unsigned u; } a; a.f = f;
  unsigned r = a.u + 0x7fffu + ((a.u >> 16) & 1u);   // RNE
  return (unsigned short)(r >> 16);
}

__device__ __forceinline__ void async16(const void* g, void* l) {
  __builtin_amdgcn_global_load_lds(
      (const __attribute__((address_space(1))) unsigned int*)g,
      (__attribute__((address_space(3))) unsigned int*)l, 16, 0, 0);
}

// ---------------- prep: fp32 -> bf16 convert (hidden states) ----------------
__global__ __launch_bounds__(256) void k_cvt(const float* __restrict__ x,
                                             unsigned short* __restrict__ y) {
  int i = (blockIdx.x * 256 + threadIdx.x) * 8;
  float4 v0 = *(const float4*)(x + i);
  float4 v1 = *(const float4*)(x + i + 4);
  u16x8 o;
  o[0] = f2bf(v0.x); o[1] = f2bf(v0.y); o[2] = f2bf(v0.z); o[3] = f2bf(v0.w);
  o[4] = f2bf(v1.x); o[5] = f2bf(v1.y); o[6] = f2bf(v1.z); o[7] = f2bf(v1.w);
  *(u16x8*)(y + i) = o;
}

// ---------------- prep: weight transpose fp32 [k][n] -> bf16 [n][k] ---------
__global__ __launch_bounds__(256) void k_tw(const float* __restrict__ W,
                                            unsigned short* __restrict__ Wt) {
  __shared__ float t[64][68];        // 68: 16B-aligned rows, conflict-light
  int tid = threadIdx.x;
  int n0 = blockIdx.x * 64, k0 = blockIdx.y * 64;
  int r = tid >> 2;                  // 0..63
  int c0 = (tid & 3) * 16;           // 0,16,32,48
  const float* src = &W[(k0 + r) * 1024 + n0 + c0];
  float4 a0 = *(const float4*)(src + 0);
  float4 a1 = *(const float4*)(src + 4);
  float4 a2 = *(const float4*)(src + 8);
  float4 a3 = *(const float4*)(src + 12);
  *(float4*)&t[r][c0 + 0]  = a0;
  *(float4*)&t[r][c0 + 4]  = a1;
  *(float4*)&t[r][c0 + 8]  = a2;
  *(float4*)&t[r][c0 + 12] = a3;
  __syncthreads();
  u16x8 o0, o1;
#pragma unroll
  for (int j = 0; j < 8; j++) { o0[j] = f2bf(t[c0 + j][r]); o1[j] = f2bf(t[c0 + 8 + j][r]); }
  *(u16x8*)&Wt[(n0 + r) * 1024 + k0 + c0]     = o0;
  *(u16x8*)&Wt[(n0 + r) * 1024 + k0 + c0 + 8] = o1;
}

// ---------------- prep: morpho bias (nearest verb + column bias) ------------
__global__ __launch_bounds__(256) void k_bias(const int* __restrict__ mt,
                                              float* __restrict__ colbias,
                                              int* __restrict__ nearest) {
  int b = blockIdx.x;
  __shared__ int sm[1024];
  int tid = threadIdx.x;
  for (int j = tid; j < 1024; j += 256) sm[j] = mt[b * 1024 + j];
  __syncthreads();
  int i = blockIdx.y * 256 + tid;
  int best = 1 << 30, bj = -1;
  for (int j = 0; j < 1024; ++j) {
    int d = (i > j) ? (i - j) : (j - i);
    int dd = (sm[j] == 2) ? d : (1 << 30);
    if (dd < best) { best = dd; bj = j; }       // strict < : first-min tie, smallest j
  }
  nearest[b * 1024 + i] = bj;                    // -1 when no verb in batch
  int m = sm[i];
  colbias[b * 1024 + i] = 0.75f * (m == 0) + 0.36f * (m == 1);
}

// ---------------- MFMA GEMM: C[r][c] = A[r][:] . Wt[c][:] + bias[c] ---------
// MODE 0: fused QKV, grid.x = 24 (wsel = x>>3), bf16 out permuted to [B,NH,S,HD]
// MODE 1: out-proj, grid.x = 8, fp32 out row-major [4096][1024]
template <int MODE>
__global__ __launch_bounds__(256) void k_gemm(
    const unsigned short* __restrict__ A,
    const unsigned short* __restrict__ WtBase,
    const float* __restrict__ bias0, const float* __restrict__ bias1,
    const float* __restrict__ bias2,
    unsigned short* __restrict__ outB, float* __restrict__ outF) {
  __shared__ unsigned short As[128 * 32];
  __shared__ unsigned short Bs[128 * 32];
  int tid = threadIdx.x, wid = tid >> 6, lane = tid & 63;
  int c = lane & 15, quad = lane >> 4;
  int m0 = blockIdx.y * 128;
  int wsel, n0;
  const unsigned short* Bt;
  const float* bias;
  if (MODE == 0) {
    wsel = blockIdx.x >> 3;
    n0 = (blockIdx.x & 7) * 128;
    Bt = WtBase + wsel * 1048576;
    bias = (wsel == 0) ? bias0 : ((wsel == 1) ? bias1 : bias2);
  } else {
    wsel = 0; n0 = blockIdx.x * 128; Bt = WtBase; bias = bias0;
  }
  int wm = (wid >> 1) * 64, wn = (wid & 1) * 64;
  const unsigned short* ga = A  + (m0 + wid * 32 + (lane >> 2)) * 1024 + (lane & 3) * 8;
  const unsigned short* gb = Bt + (n0 + wid * 32 + (lane >> 2)) * 1024 + (lane & 3) * 8;
  unsigned short* lA = &As[wid * 32 * 32];   // wave-uniform base
  unsigned short* lB = &Bs[wid * 32 * 32];

  f32x4 acc[4][4];
#pragma unroll
  for (int i = 0; i < 4; i++)
#pragma unroll
    for (int j = 0; j < 4; j++) acc[i][j] = (f32x4){0.f, 0.f, 0.f, 0.f};

  for (int k0 = 0; k0 < 1024; k0 += 32) {
    async16(ga + k0,             lA);
    async16(ga + 16 * 1024 + k0, lA + 16 * 32);
    async16(gb + k0,             lB);
    async16(gb + 16 * 1024 + k0, lB + 16 * 32);
    __syncthreads();
    s16x8 af[4], bf[4];
#pragma unroll
    for (int i = 0; i < 4; i++) af[i] = *(const s16x8*)&As[(wm + i * 16 + c) * 32 + quad * 8];
#pragma unroll
    for (int j = 0; j < 4; j++) bf[j] = *(const s16x8*)&Bs[(wn + j * 16 + c) * 32 + quad * 8];
#pragma unroll
    for (int i = 0; i < 4; i++)
#pragma unroll
      for (int j = 0; j < 4; j++)
        acc[i][j] = __builtin_amdgcn_mfma_f32_16x16x32_bf16(af[i], bf[j], acc[i][j], 0, 0, 0);
    __syncthreads();
  }

#pragma unroll
  for (int j = 0; j < 4; j++) {
    int col = n0 + wn + j * 16 + c;
    float bv = bias[col];
    int h = col >> 6, d = col & 63;
#pragma unroll
    for (int i = 0; i < 4; i++) {
      int row = m0 + wm + i * 16 + quad * 4;
#pragma unroll
      for (int r = 0; r < 4; r++) {
        float v = acc[i][j][r] + bv;
        int rr = row + r;
        if (MODE == 0) {
          int bb = rr >> 10, s = rr & 1023;
          outB[(size_t)wsel * 4194304 + (((bb * 16 + h) * 1024 + s) * 64) + d] = f2bf(v);
        } else {
          outF[rr * 1024 + col] = v;
        }
      }
    }
  }
}

// ---------------- V transpose: [b,h,s,d] -> [b,h,d,s] (bf16) ----------------
__global__ __launch_bounds__(256) void k_tv(const unsigned short* __restrict__ V,
                                            unsigned short* __restrict__ Vt) {
  int bh = blockIdx.y, s0 = blockIdx.x * 64;
  __shared__ unsigned short t[64][72];
  int tid = threadIdx.x;
  int r = tid >> 2, c0 = (tid & 3) * 16;
  const unsigned short* src = &V[(bh * 1024 + s0 + r) * 64 + c0];
  u16x8 a = *(const u16x8*)(src);
  u16x8 b = *(const u16x8*)(src + 8);
  *(u16x8*)&t[r][c0]     = a;
  *(u16x8*)&t[r][c0 + 8] = b;
  __syncthreads();
  u16x8 o0, o1;
#pragma unroll
  for (int j = 0; j < 8; j++) { o0[j] = t[c0 + j][r]; o1[j] = t[c0 + 8 + j][r]; }
  *(u16x8*)&Vt[(bh * 64 + r) * 1024 + s0 + c0]     = o0;
  *(u16x8*)&Vt[(bh * 64 + r) * 1024 + s0 + c0 + 8] = o1;
}

// ---------------- Flash attention with morpho bias --------------------------
// Computes S^T = K.Q^T per 64-key chunk (softmax stats = 2 shuffles), online
// softmax, P via per-wave LDS round-trip (C-layout -> A-layout), O = P.V.
__global__ __launch_bounds__(256) void k_attn(
    const unsigned short* __restrict__ Q, const unsigned short* __restrict__ K,
    const unsigned short* __restrict__ Vt, const float* __restrict__ colbias,
    const int* __restrict__ nearest, unsigned short* __restrict__ AO) {
  __shared__ unsigned short Ks[64 * 72];       // [key][d] pad 72
  __shared__ unsigned short Vs[64 * 72];       // [d][key] pad 72
  __shared__ unsigned short Ps[4][32 * 72];    // per-wave [q][key] pad 72
  int tid = threadIdx.x, wid = tid >> 6, lane = tid & 63;
  int c = lane & 15, quad = lane >> 4;
  int qt = blockIdx.x, bh = blockIdx.y;
  int b = bh >> 4, h = bh & 15;
  int q0 = qt * 128, wq = wid * 32;
  const unsigned short* Qg = Q  + (size_t)(bh * 1024 + q0 + wq) * 64;
  const unsigned short* Kg = K  + (size_t)bh * 1024 * 64;
  const unsigned short* Vg = Vt + (size_t)bh * 64 * 1024;

  s16x8 qf[2][2];
#pragma unroll
  for (int nt = 0; nt < 2; nt++)
#pragma unroll
    for (int ks = 0; ks < 2; ks++)
      qf[nt][ks] = *(const s16x8*)&Qg[(nt * 16 + c) * 64 + ks * 32 + quad * 8];

  int nq[2];
  nq[0] = nearest[b * 1024 + q0 + wq + c];
  nq[1] = nearest[b * 1024 + q0 + wq + 16 + c];

  f32x4 o[2][4];
#pragma unroll
  for (int i = 0; i < 2; i++)
#pragma unroll
    for (int j = 0; j < 4; j++) o[i][j] = (f32x4){0.f, 0.f, 0.f, 0.f};
  float mrun[2] = {-1e30f, -1e30f};
  float lrun[2] = {0.f, 0.f};

  int srow = tid >> 3, scol = (tid & 7) * 8;

  for (int kc = 0; kc < 16; ++kc) {
#pragma unroll
    for (int it = 0; it < 2; ++it) {
      int r2 = it * 32 + srow;
      *(u16x8*)&Ks[r2 * 72 + scol] = *(const u16x8*)&Kg[(kc * 64 + r2) * 64 + scol];
      *(u16x8*)&Vs[r2 * 72 + scol] = *(const u16x8*)&Vg[r2 * 1024 + kc * 64 + scol];
    }
    __syncthreads();

    // S^T = K . Q^T  (row = key, col = q)
    f32x4 st[4][2];
#pragma unroll
    for (int mt = 0; mt < 4; mt++)
#pragma unroll
      for (int nt = 0; nt < 2; nt++) st[mt][nt] = (f32x4){0.f, 0.f, 0.f, 0.f};
#pragma unroll
    for (int mt = 0; mt < 4; mt++)
#pragma unroll
      for (int ks = 0; ks < 2; ks++) {
        s16x8 a = *(const s16x8*)&Ks[(mt * 16 + c) * 72 + ks * 32 + quad * 8];
#pragma unroll
        for (int nt = 0; nt < 2; nt++)
          st[mt][nt] = __builtin_amdgcn_mfma_f32_16x16x32_bf16(a, qf[nt][ks], st[mt][nt], 0, 0, 0);
      }

    // scale + morpho bias
#pragma unroll
    for (int mt = 0; mt < 4; mt++) {
      f32x4 cb = *(const f32x4*)&colbias[b * 1024 + kc * 64 + mt * 16 + quad * 4];
#pragma unroll
      for (int r = 0; r < 4; r++) {
        int keyg = kc * 64 + mt * 16 + quad * 4 + r;
#pragma unroll
        for (int nt = 0; nt < 2; nt++)
          st[mt][nt][r] = st[mt][nt][r] * SCALEc + cb[r] + ((keyg == nq[nt]) ? 2.0f : 0.0f);
      }
    }

    // online softmax (per q = nt*16 + c; quads reduced by 2 shuffles)
    float alph[2];
#pragma unroll
    for (int nt = 0; nt < 2; nt++) {
      float cmax = st[0][nt][0];
#pragma unroll
      for (int mt = 0; mt < 4; mt++)
#pragma unroll
        for (int r = 0; r < 4; r++) cmax = fmaxf(cmax, st[mt][nt][r]);
      cmax = fmaxf(cmax, __shfl_xor(cmax, 16, 64));
      cmax = fmaxf(cmax, __shfl_xor(cmax, 32, 64));
      float mnew = fmaxf(mrun[nt], cmax);
      float a_ = __expf(mrun[nt] - mnew);
      float csum = 0.f;
#pragma unroll
      for (int mt = 0; mt < 4; mt++)
#pragma unroll
        for (int r = 0; r < 4; r++) {
          float e = __expf(st[mt][nt][r] - mnew);
          st[mt][nt][r] = e; csum += e;
        }
      csum += __shfl_xor(csum, 16, 64);
      csum += __shfl_xor(csum, 32, 64);
      lrun[nt] = lrun[nt] * a_ + csum;
      mrun[nt] = mnew; alph[nt] = a_;
    }

    // rescale O (alpha redistributed to C-layout rows via shuffle)
#pragma unroll
    for (int mtq = 0; mtq < 2; mtq++)
#pragma unroll
      for (int r = 0; r < 4; r++) {
        float aq = __shfl(alph[mtq], quad * 4 + r, 64);
#pragma unroll
        for (int ntd = 0; ntd < 4; ntd++) o[mtq][ntd][r] *= aq;
      }

    // P: C-layout -> LDS [q][key] (A-layout source)
#pragma unroll
    for (int mt = 0; mt < 4; mt++)
#pragma unroll
      for (int nt = 0; nt < 2; nt++) {
        u16x4 pk;
#pragma unroll
        for (int r = 0; r < 4; r++) pk[r] = f2bf(st[mt][nt][r]);
        *(u16x4*)&Ps[wid][(nt * 16 + c) * 72 + mt * 16 + quad * 4] = pk;
      }
    __asm__ volatile("s_waitcnt lgkmcnt(0)" ::: "memory");

    // O += P . V
#pragma unroll
    for (int ks = 0; ks < 2; ks++) {
      s16x8 pa[2];
#pragma unroll
      for (int mtq = 0; mtq < 2; mtq++)
        pa[mtq] = *(const s16x8*)&Ps[wid][(mtq * 16 + c) * 72 + ks * 32 + quad * 8];
#pragma unroll
      for (int ntd = 0; ntd < 4; ntd++) {
        s16x8 vb = *(const s16x8*)&Vs[(ntd * 16 + c) * 72 + ks * 32 + quad * 8];
#pragma unroll
        for (int mtq = 0; mtq < 2; mtq++)
          o[mtq][ntd] = __builtin_amdgcn_mfma_f32_16x16x32_bf16(pa[mtq], vb, o[mtq][ntd], 0, 0, 0);
      }
    }
    __syncthreads();
  }

  float linv[2] = {1.0f / lrun[0], 1.0f / lrun[1]};
#pragma unroll
  for (int mtq = 0; mtq < 2; mtq++)
#pragma unroll
    for (int r = 0; r < 4; r++) {
      float lq = __shfl(linv[mtq], quad * 4 + r, 64);
      int row = b * 1024 + q0 + wq + mtq * 16 + quad * 4 + r;
#pragma unroll
      for (int ntd = 0; ntd < 4; ntd++)
        AO[(size_t)row * 1024 + h * 64 + ntd * 16 + c] = f2bf(o[mtq][ntd][r] * lq);
    }
}

// ---------------------------------------------------------------------------
extern "C" void kernel_launch(void* const* d_in, const int* in_sizes, int n_in,
                              void* d_out, int out_size, void* d_ws, size_t ws_size,
                              hipStream_t stream) {
  const float* hs     = (const float*)d_in[0];
  const int*   morpho = (const int*)d_in[1];
  const float* Wq = (const float*)d_in[2];
  const float* bq = (const float*)d_in[3];
  const float* Wk = (const float*)d_in[4];
  const float* bk = (const float*)d_in[5];
  const float* Wv = (const float*)d_in[6];
  const float* bv = (const float*)d_in[7];
  const float* Wo = (const float*)d_in[8];
  const float* bo = (const float*)d_in[9];
  float* out = (float*)d_out;

  char* ws = (char*)d_ws;
  unsigned short* hsb = (unsigned short*)(ws);                    // 8 MB [4096][1024]
  unsigned short* Wt  = (unsigned short*)(ws + (8u << 20));       // 8 MB [4][1024][1024]
  unsigned short* Qb  = (unsigned short*)(ws + (16u << 20));      // 8 MB [B,NH,S,HD]
  // Kb = Qb + 4M elems, Vb = Qb + 8M elems (contiguous, indexed by wsel in k_gemm)
  unsigned short* Kb  = (unsigned short*)(ws + (24u << 20));
  unsigned short* Vb  = (unsigned short*)(ws + (32u << 20));
  unsigned short* Vtb = (unsigned short*)(ws + (40u << 20));      // 8 MB [B,NH,HD,S]
  float* colbias      = (float*)(ws + (48u << 20));               // 16 KB
  int*   nearestp     = (int*)(ws + (48u << 20) + (16u << 10));   // 16 KB
  unsigned short* AO  = hsb;  // reuse: hs_bf16 dead after QKV GEMM

  k_cvt<<<2048, 256, 0, stream>>>(hs, hsb);
  k_tw<<<dim3(16, 16), 256, 0, stream>>>(Wq, Wt + 0 * 1048576);
  k_tw<<<dim3(16, 16), 256, 0, stream>>>(Wk, Wt + 1 * 1048576);
  k_tw<<<dim3(16, 16), 256, 0, stream>>>(Wv, Wt + 2 * 1048576);
  k_tw<<<dim3(16, 16), 256, 0, stream>>>(Wo, Wt + 3 * 1048576);
  k_bias<<<dim3(4, 4), 256, 0, stream>>>(morpho, colbias, nearestp);
  k_gemm<0><<<dim3(24, 32), 256, 0, stream>>>(hsb, Wt, bq, bk, bv, Qb, nullptr);
  k_tv<<<dim3(16, 64), 256, 0, stream>>>(Vb, Vtb);
  k_attn<<<dim3(8, 64), 256, 0, stream>>>(Qb, Kb, Vtb, colbias, nearestp, AO);
  k_gemm<1><<<dim3(8, 32), 256, 0, stream>>>(AO, Wt + 3 * 1048576, bo, nullptr, nullptr,
                                             nullptr, out);
  (void)in_sizes; (void)n_in; (void)out_size; (void)ws_size; (void)Kb; (void)Vb;
}